// Round 9
// baseline (263.084 us; speedup 1.0000x reference)
//
#include <hip/hip_runtime.h>
#include <math.h>

#ifndef M_PI
#define M_PI 3.14159265358979323846
#endif

// Shapes: x [64,1024,14,14]; w1 [256,1024]; w2 [256,256,3,3]; w3 [1024,256]
#define NB   64
#define NCOL 12544

typedef __attribute__((ext_vector_type(4))) int int4v;

// ---------------- workspace layout (float offsets) ----------------
static const size_t OF_OUT = 0;            // conv1/conv2 fp32 NHWC out [12544][256]
static const size_t OF_XC  = 3211264;      // x codes i8 NHWC [64][196][1024]
static const size_t OF_Z1P = 6422528;      // z1 codes i8 padded [64][16][16][256]
static const size_t OF_WQ1 = 8273920;      // w1 codes i8 [256][1024]
static const size_t OF_WQ2 = 8339456;      // w2 codes i8 [256][9*256]
static const size_t OF_WQ3 = 8486912;      // w3 codes i8 [1024][256]
static const size_t OF_R1  = 8552448;
static const size_t OF_R2  = 8552704;
static const size_t OF_R3  = 8552960;
static const size_t OF_T2  = 8553984;      // 256*8 tap aggregates
static const size_t OF_CX  = 8556032;      // 12544
static const size_t OF_U2  = 8568576;      // 16384 (padded rowsums [64][16][16])
// stage stats (compact):
static const size_t OF_SD1 = 8610048;      // double[256]  (512 floats)
static const size_t OF_SD2 = 8610560;      // double[256]
static const size_t OF_SD3 = 8611072;      // double[1024] (2048 floats)
static const size_t OF_MN1 = 8613120;      // uint[256] min keys
static const size_t OF_MX1 = 8613376;      // uint[256] max keys
static const size_t OF_MN2 = 8613632;
static const size_t OF_MX2 = 8613888;
static const size_t OF_MN3 = 8614144;      // uint[1024]
static const size_t OF_MX3 = 8615168;      // uint[1024]
static const size_t OF_PMM = 9061632;      // minmax partials
static const size_t OF_ST  = 9068800;      // 64 misc floats (fq params)

__device__ __forceinline__ float fqv(float v, float mn, float sc) {
    float t = (v - mn) / sc;
    t = fminf(fmaxf(t, 0.0f), 255.0f);
    return rintf(t) * sc + mn;
}
// centered code (integer-valued in [-128,127])
__device__ __forceinline__ float codef(float v, float mn, float sc) {
    float t = (v - mn) / sc;
    t = fminf(fmaxf(t, 0.0f), 255.0f);
    return rintf(t) - 128.0f;
}
__device__ __forceinline__ unsigned short f2bf(float f) { return (unsigned short)(__float_as_uint(f) >> 16); }
__device__ __forceinline__ float bf2f(unsigned short u) { return __uint_as_float(((unsigned)u) << 16); }
__device__ __forceinline__ int pack4(float a, float b, float c, float d) {
    return (int)(unsigned char)(signed char)(int)a | ((int)(unsigned char)(signed char)(int)b << 8) |
           ((int)(unsigned char)(signed char)(int)c << 16) | ((int)(unsigned char)(signed char)(int)d << 24);
}
__device__ __forceinline__ void glds16(const void* g, void* l) {
    __builtin_amdgcn_global_load_lds((const __attribute__((address_space(1))) unsigned int*)g,
                                     (__attribute__((address_space(3))) unsigned int*)l, 16, 0, 0);
}
// monotone float<->uint key map (for atomicMin/Max on floats)
__device__ __forceinline__ unsigned fkey(float f) {
    unsigned u = __float_as_uint(f);
    return (u & 0x80000000u) ? ~u : (u | 0x80000000u);
}
__device__ __forceinline__ float unfkey(unsigned k) {
    unsigned u = (k & 0x80000000u) ? (k & 0x7FFFFFFFu) : ~k;
    return __uint_as_float(u);
}

// cooperative (256-thread) block min/max reduce; returns uniform values
__device__ __forceinline__ void blk_minmax(float& mn, float& mx, volatile float* scr) {
    for (int o = 32; o; o >>= 1) {
        mn = fminf(mn, __shfl_down(mn, o, 64));
        mx = fmaxf(mx, __shfl_down(mx, o, 64));
    }
    int lane = threadIdx.x & 63, wv = threadIdx.x >> 6;
    __syncthreads();
    if (lane == 0) { scr[wv] = mn; scr[4 + wv] = mx; }
    __syncthreads();
    mn = fminf(fminf(scr[0], scr[1]), fminf(scr[2], scr[3]));
    mx = fmaxf(fmaxf(scr[4], scr[5]), fmaxf(scr[6], scr[7]));
}

// derive (mn, scale) of one tensor from its minmax partials (exact: fmin/fmax
// reductions are order-independent -> bit-identical to the old k_fqparams2).
__device__ __forceinline__ void derive_fq(const float* __restrict__ Pmm, int base, int nb,
                                          volatile float* scr, float& mn_o, float& sc_o) {
    float mn = INFINITY, mx = -INFINITY;
    for (int i = threadIdx.x; i < nb; i += 256) {
        mn = fminf(mn, Pmm[base + 2 * i]);
        mx = fmaxf(mx, Pmm[base + 2 * i + 1]);
    }
    blk_minmax(mn, mx, scr);
    mn_o = mn;
    sc_o = fmaxf((mx - mn) / 255.0f, 1e-8f);
}

// recompute range_norm params of a finished stage from compact stats.
template <int C>
__device__ void stage_params(const float* __restrict__ gamma, const float* __restrict__ beta,
                             const double* __restrict__ sumd, const unsigned* __restrict__ mnk,
                             const unsigned* __restrict__ mxk, float scale_fix,
                             float* lmean, float* lsg, volatile float* scr,
                             float& zmn, float& zsc) {
    int t = threadIdx.x;
    float gmn = INFINITY, gmx = -INFINITY;
    for (int c = t; c < C; c += 256) {
        float g = gamma[c];
        gmn = fminf(gmn, g); gmx = fmaxf(gmx, g);
    }
    blk_minmax(gmn, gmx, scr);
    float gsc = fmaxf((gmx - gmn) / 255.0f, 1e-8f);
    float qmn = INFINITY, qmx = -INFINITY;
    for (int c = t; c < C; c += 256) {
        float mean = (float)sumd[c] / 12544.0f;
        float cmn = unfkey(mnk[c]), cmx = unfkey(mxk[c]);
        float rng = cmx - cmn;
        float qg = fqv(gamma[c], gmn, gsc);
        float s = qg / (rng * scale_fix + 1e-5f);
        if (lmean) { lmean[c] = mean; lsg[c] = s; }
        float b = beta[c];
        float lo = (cmn - mean) * s + b;
        float hi = (cmx - mean) * s + b;
        qmn = fminf(qmn, fminf(lo, hi));
        qmx = fmaxf(qmx, fmaxf(lo, hi));
    }
    blk_minmax(qmn, qmx, scr);
    zmn = qmn;
    zsc = fmaxf((qmx - qmn) / 255.0f, 1e-8f);
}

// ---------------- fused min/max over 4 tensors -> per-block partials + workspace init ----------------
__global__ __launch_bounds__(256) void k_minmax_all(const float4* __restrict__ x, const float4* __restrict__ w1,
                                                    const float4* __restrict__ w2, const float4* __restrict__ w3,
                                                    float* __restrict__ Pmm, float* __restrict__ Wf) {
    // --- init section: zero z1p/CX/U2 + stage stats, seed min/max keys ---
    {
        unsigned g = blockIdx.x * 256 + threadIdx.x;   // 0..327679
        int* zp = (int*)(Wf + OF_Z1P);
        for (unsigned i = g; i < 1048576u; i += 327680u) zp[i] = 0;
        if (g < 12544u) Wf[OF_CX + g] = 0.0f;
        if (g < 16384u) Wf[OF_U2 + g] = 0.0f;
        if (g < 3072u)  ((int*)(Wf + OF_SD1))[g] = 0;
        if (g < 256u) {
            ((unsigned*)(Wf + OF_MN1))[g] = 0xFF800000u;
            ((unsigned*)(Wf + OF_MX1))[g] = 0x007FFFFFu;
            ((unsigned*)(Wf + OF_MN2))[g] = 0xFF800000u;
            ((unsigned*)(Wf + OF_MX2))[g] = 0x007FFFFFu;
        }
        if (g < 1024u) {
            ((unsigned*)(Wf + OF_MN3))[g] = 0xFF800000u;
            ((unsigned*)(Wf + OF_MX3))[g] = 0x007FFFFFu;
        }
    }
    int b = blockIdx.x;
    const float4* p; int lb, nb, n4, base;
    if (b < 1024)      { p = x;  lb = b;        nb = 1024; n4 = 3211264; base = 0; }
    else if (b < 1088) { p = w1; lb = b - 1024; nb = 64;   n4 = 65536;   base = 2048; }
    else if (b < 1216) { p = w2; lb = b - 1088; nb = 128;  n4 = 147456;  base = 2176; }
    else               { p = w3; lb = b - 1216; nb = 64;   n4 = 65536;   base = 2432; }
    float mn = INFINITY, mx = -INFINITY;
    for (int i = lb * 256 + threadIdx.x; i < n4; i += nb * 256) {
        float4 v = p[i];
        mn = fminf(mn, fminf(fminf(v.x, v.y), fminf(v.z, v.w)));
        mx = fmaxf(mx, fmaxf(fmaxf(v.x, v.y), fmaxf(v.z, v.w)));
    }
    for (int o = 32; o; o >>= 1) {
        mn = fminf(mn, __shfl_down(mn, o, 64));
        mx = fmaxf(mx, __shfl_down(mx, o, 64));
    }
    __shared__ float smn[4], smx[4];
    int lane = threadIdx.x & 63, w = threadIdx.x >> 6;
    if (lane == 0) { smn[w] = mn; smx[w] = mx; }
    __syncthreads();
    if (threadIdx.x == 0) {
        for (int i = 1; i < 4; i++) { mn = fminf(mn, smn[i]); mx = fmaxf(mx, smx[i]); }
        Pmm[base + lb * 2]     = mn;
        Pmm[base + lb * 2 + 1] = mx;
    }
}

// ---------------- k_prep: x->NHWC i8 codes + CX | weight coding | sf persist ----------------
// Merged k_code0 (0..1791) + k_wcode_all (1792..3071 1x1, 3072..3327 3x3) +
// k_fqparams2 (block 3328 persists sf for downstream kernels). All blocks derive
// their own fq params from Pmm in-block (fmin/fmax reduce: bit-exact).
__global__ __launch_bounds__(256) void k_prep(const float* __restrict__ x, signed char* __restrict__ xdst,
                                              const float* __restrict__ Pmm, float* __restrict__ sf,
                                              float* __restrict__ CX,
                                              const float* __restrict__ w1, const float* __restrict__ w2,
                                              const float* __restrict__ w3,
                                              signed char* __restrict__ wq1, signed char* __restrict__ wq2,
                                              signed char* __restrict__ wq3,
                                              float* __restrict__ R1, float* __restrict__ R2,
                                              float* __restrict__ R3, float* __restrict__ T8) {
    __shared__ float scr8[8];
    int t = threadIdx.x;
    int lane = t & 63, wv = t >> 6;
    if (blockIdx.x == 3328) {
        // persist fq params (old k_fqparams2 body) for conv1/conv3/final
        __shared__ float sa[4], sb[4];
        const int nbs[4]   = {1024, 64, 128, 64};
        const int bases[4] = {0, 2048, 2176, 2432};
        for (int ten = 0; ten < 4; ten++) {
            float mn = INFINITY, mx = -INFINITY;
            for (int i = t; i < nbs[ten]; i += 256) {
                mn = fminf(mn, Pmm[bases[ten] + 2 * i]);
                mx = fmaxf(mx, Pmm[bases[ten] + 2 * i + 1]);
            }
            for (int o = 32; o; o >>= 1) {
                mn = fminf(mn, __shfl_down(mn, o, 64));
                mx = fmaxf(mx, __shfl_down(mx, o, 64));
            }
            if (lane == 0) { sa[wv] = mn; sb[wv] = mx; }
            __syncthreads();
            if (t == 0) {
                mn = fminf(fminf(sa[0], sa[1]), fminf(sa[2], sa[3]));
                mx = fmaxf(fmaxf(sb[0], sb[1]), fmaxf(sb[2], sb[3]));
                sf[8 + 3 * ten] = mn;
                sf[9 + 3 * ten] = fmaxf((mx - mn) / 255.0f, 1e-8f);
            }
            __syncthreads();
        }
        return;
    }
    if (blockIdx.x < 1792) {
        // ---- code0 unit ----
        float qmn, qsc;
        derive_fq(Pmm, 0, 1024, scr8, qmn, qsc);
        __shared__ unsigned short lt[28][264];
        int u = blockIdx.x;
        int n = u / 28, r = u - n * 28;
        int hw0 = (r % 7) * 28, cq = (r / 7) * 256;
        const float* sp = x + ((size_t)n * 1024 + cq) * 196 + hw0;
        for (int i = t; i < 7168; i += 256) {
            int c = i / 28, hw = i - c * 28;
            lt[hw][c] = f2bf(codef(sp[(size_t)c * 196 + hw], qmn, qsc));
        }
        __syncthreads();
        int c0 = lane * 4;
#pragma unroll
        for (int s = 0; s < 7; s++) {
            int i = s * 4 + wv;
            int pk = pack4(bf2f(lt[i][c0]), bf2f(lt[i][c0 + 1]), bf2f(lt[i][c0 + 2]), bf2f(lt[i][c0 + 3]));
            *(int*)&xdst[((size_t)n * 196 + hw0 + i) * 1024 + cq + c0] = pk;
        }
        for (int i = wv; i < 28; i += 4) {
            float s = bf2f(lt[i][lane]) + bf2f(lt[i][lane + 64]) +
                      bf2f(lt[i][lane + 128]) + bf2f(lt[i][lane + 192]);
            for (int o = 32; o; o >>= 1) s += __shfl_down(s, o, 64);
            if (lane == 0) atomicAdd(&CX[n * 196 + hw0 + i], s);
        }
        return;
    }
    // ---- wcode unit ----
    __shared__ float sh[64];
    int b = blockIdx.x - 1792;
    if (b < 1280) {
        const float* w; signed char* wc; float* R; int K, co;
        float mn, s;
        if (b < 256) { w = w1; wc = wq1; R = R1; K = 1024; co = b;       derive_fq(Pmm, 2048, 64, scr8, mn, s); }
        else         { w = w3; wc = wq3; R = R3; K = 256;  co = b - 256; derive_fq(Pmm, 2432, 64, scr8, mn, s); }
        float sum = 0.f;
        for (int k0 = t * 4; k0 < K; k0 += 1024) {
            float4 v = *(const float4*)&w[(size_t)co * K + k0];
            float c0 = codef(v.x, mn, s), c1 = codef(v.y, mn, s), c2 = codef(v.z, mn, s), c3 = codef(v.w, mn, s);
            *(int*)&wc[(size_t)co * K + k0] = pack4(c0, c1, c2, c3);
            sum += c0 + c1 + c2 + c3;
        }
        for (int o = 32; o; o >>= 1) sum += __shfl_down(sum, o, 64);
        if (lane == 0) sh[wv] = sum;
        __syncthreads();
        if (t == 0) R[co] = sh[0] + sh[1] + sh[2] + sh[3];
    } else {
        float mn, s;
        derive_fq(Pmm, 2176, 128, scr8, mn, s);
        int co = b - 1280, ci = t;
        float tp[9];
#pragma unroll
        for (int p = 0; p < 9; p++) {
            float c = codef(w2[((size_t)co * 256 + ci) * 9 + p], mn, s);
            wq2[(size_t)co * 2304 + p * 256 + ci] = (signed char)(int)c;
            tp[p] = c;
        }
        float* red = sh;      // [4][9]
        float* sT = sh + 40;  // [9]
#pragma unroll
        for (int p = 0; p < 9; p++) {
            float v = tp[p];
            for (int o = 32; o; o >>= 1) v += __shfl_down(v, o, 64);
            if (lane == 0) red[wv * 9 + p] = v;
        }
        __syncthreads();
        if (ci < 9) sT[ci] = red[ci] + red[9 + ci] + red[18 + ci] + red[27 + ci];
        __syncthreads();
        if (ci == 0) {
            float T0 = sT[0], T1 = sT[1], T2 = sT[2], T3 = sT[3],
                  T5 = sT[5], T6 = sT[6], T7 = sT[7], T8v = sT[8];
            R2[co] = T0 + T1 + T2 + T3 + sT[4] + T5 + T6 + T7 + T8v;
            float* o = &T8[co * 8];
            o[0] = T0 + T1 + T2;   // top
            o[1] = T6 + T7 + T8v;  // bot
            o[2] = T0 + T3 + T6;   // left
            o[3] = T2 + T5 + T8v;  // right
            o[4] = T0; o[5] = T2; o[6] = T6; o[7] = T8v;
        }
    }
}

// ---------------- NHWC elementwise norm+quant -> i8 codes + rowsum (stage 1 only) ----------------
template <int PAD>
__global__ __launch_bounds__(256) void k_codeE(const float* __restrict__ src, signed char* __restrict__ dst,
                                               const float* __restrict__ gamma, const float* __restrict__ beta_g,
                                               const double* __restrict__ sumd, const unsigned* __restrict__ mnk,
                                               const unsigned* __restrict__ mxk, float scale_fix,
                                               float* __restrict__ rowsum) {
    __shared__ __align__(16) float lmean[256];
    __shared__ __align__(16) float lsg[256];
    __shared__ float scr[8];
    float qmn, qsc;
    stage_params<256>(gamma, beta_g, sumd, mnk, mxk, scale_fix, lmean, lsg, scr, qmn, qsc);
    __syncthreads();
    int t = threadIdx.x, lane = t & 63, wv = t >> 6;
    int c4 = lane * 4;
    float4 m4 = *(const float4*)&lmean[c4];
    float4 s4 = *(const float4*)&lsg[c4];
    float4 b4 = *(const float4*)&beta_g[c4];
#pragma unroll
    for (int r = 0; r < 4; r++) {
        int j = blockIdx.x * 16 + wv * 4 + r;
        float4 v = *(const float4*)&src[(size_t)j * 256 + c4];
        float c0 = codef((v.x - m4.x) * s4.x + b4.x, qmn, qsc);
        float c1 = codef((v.y - m4.y) * s4.y + b4.y, qmn, qsc);
        float c2 = codef((v.z - m4.z) * s4.z + b4.z, qmn, qsc);
        float c3 = codef((v.w - m4.w) * s4.w + b4.w, qmn, qsc);
        int n = j / 196, hw = j - n * 196, h = hw / 14, w = hw - (hw / 14) * 14;
        size_t di;
        if (PAD) di = (((size_t)n * 16 + h + 1) * 16 + (w + 1)) * 256 + c4;
        else     di = (size_t)j * 256 + c4;
        *(int*)&dst[di] = pack4(c0, c1, c2, c3);
        float s = c0 + c1 + c2 + c3;
        for (int o = 32; o; o >>= 1) s += __shfl_down(s, o, 64);
        if (lane == 0) {
            if (PAD) rowsum[((size_t)n * 16 + h + 1) * 16 + (w + 1)] = s;
            else     rowsum[j] = s;
        }
    }
}

// ---------------- conv1/conv2: i8 MFMA, M=128 j, N=64 co, BK=128, dbuf ----------------
// 1D grid 392 with XCD-grouping swizzle (R4: same-A blocks on one XCD -> L2 reuse).
// MODE 1: 9-tap of U2 computed ONCE per block into Vl LDS.
template <int MODE>
__global__ __launch_bounds__(256, 2) void k_conv12(const signed char* __restrict__ Acts,
                                                   const signed char* __restrict__ Wts,
                                                   const float* __restrict__ R, const float* __restrict__ T8,
                                                   const float* __restrict__ Cj,
                                                   const float* __restrict__ pw, const float* __restrict__ pz,
                                                   const float* __restrict__ pzg, const float* __restrict__ pzb,
                                                   const double* __restrict__ pzsum,
                                                   const unsigned* __restrict__ pzmn,
                                                   const unsigned* __restrict__ pzmx, float scale_fix,
                                                   float* __restrict__ outNHWC, int K,
                                                   double* __restrict__ Sumd, unsigned* __restrict__ Mnk,
                                                   unsigned* __restrict__ Mxk) {
    __shared__ __align__(16) signed char As[2 * 16384];   // 2 x 128 rows x 128B
    __shared__ __align__(16) signed char Bs[2 * 8192];    // 2 x 64 rows x 128B
    __shared__ float Lst[2][64][3];
    __shared__ float pscr[8];
    __shared__ float Vl[128];
    int tid = threadIdx.x, lane = tid & 63, wave = tid >> 6;
    int wm = wave >> 1, wn = wave & 1;
    // XCD-grouping swizzle (392 = 49 tiles/XCD * 8 XCDs, bijective)
    int bid = blockIdx.x;
    int xcd = bid & 7, slot = bid >> 3;
    int tile = xcd * 49 + slot;
    int jb = (tile >> 2) * 128, cob = (tile & 3) * 64;
    int sr = tid >> 3, spos = tid & 7, sc = spos ^ (sr & 7);

    const signed char* aq[4];
#pragma unroll
    for (int q = 0; q < 4; q++) {
        int j = jb + q * 32 + sr;
        if (MODE == 0) aq[q] = Acts + (size_t)j * K + sc * 16;
        else {
            int n = j / 196, hw = j - n * 196, h = hw / 14, w = hw - (hw / 14) * 14;
            aq[q] = Acts + (((size_t)n * 16 + h) * 16 + w) * 256 + sc * 16;
        }
    }
    const signed char* bq[2];
#pragma unroll
    for (int q = 0; q < 2; q++) bq[q] = Wts + (size_t)(cob + q * 32 + sr) * K + sc * 16;

    int nk = K >> 7;
    auto stage = [&](int b, int ks) {
        size_t koA;
        if (MODE == 0) koA = (size_t)ks << 7;
        else {
            int k = ks << 7;
            int p = k >> 8, kin = k & 255;
            int rr = p / 3, ss = p - 3 * rr;
            koA = (size_t)(rr * 16 + ss) * 256 + kin;
        }
#pragma unroll
        for (int q = 0; q < 4; q++)
            glds16(aq[q] + koA, &As[b * 16384 + (q * 32 + sr) * 128 + spos * 16]);
#pragma unroll
        for (int q = 0; q < 2; q++)
            glds16(bq[q] + ((size_t)ks << 7), &Bs[b * 8192 + (q * 32 + sr) * 128 + spos * 16]);
    };

    // issue stage 0 first so its latency hides under the params/Vl work (MODE 1)
    stage(0, 0);
    float zmn = 0.f, zsc = 0.f;
    if (MODE == 1) {
        stage_params<256>(pzg, pzb, pzsum, pzmn, pzmx, scale_fix, nullptr, nullptr, pscr, zmn, zsc);
        if (tid < 128) {
            int j = jb + tid;
            int n_ = j / 196, hw_ = j - n_ * 196, h_ = hw_ / 14, w_ = hw_ - (hw_ / 14) * 14;
            const float* u = Cj + n_ * 256 + h_ * 16 + w_;
            Vl[tid] = u[0] + u[1] + u[2] + u[16] + u[17] + u[18] + u[32] + u[33] + u[34];
        }
    }

    int4v acc[4][2];
#pragma unroll
    for (int mi = 0; mi < 4; mi++)
#pragma unroll
        for (int ni = 0; ni < 2; ni++) acc[mi][ni] = (int4v)0;

    int l15 = lane & 15, kq = lane >> 4, sw = l15 & 7;
    for (int ks = 0; ks < nk; ks++) {
        __syncthreads();
        if (ks + 1 < nk) stage((ks + 1) & 1, ks + 1);
        int b = ks & 1;
#pragma unroll
        for (int kc = 0; kc < 2; kc++) {
            int col = ((kc * 4 + kq) ^ sw) << 4;
            int4v a[4], bb[2];
#pragma unroll
            for (int mi = 0; mi < 4; mi++)
                a[mi] = *(const int4v*)&As[b * 16384 + (wm * 64 + mi * 16 + l15) * 128 + col];
#pragma unroll
            for (int ni = 0; ni < 2; ni++)
                bb[ni] = *(const int4v*)&Bs[b * 8192 + (wn * 32 + ni * 16 + l15) * 128 + col];
#pragma unroll
            for (int mi = 0; mi < 4; mi++)
#pragma unroll
                for (int ni = 0; ni < 2; ni++)
                    acc[mi][ni] = __builtin_amdgcn_mfma_i32_16x16x64_i8(a[mi], bb[ni], acc[mi][ni], 0, 0, 0);
        }
    }

    // epilogue: value = aw*az*S + aw*bz*(R-PT) + bw*az*Cj + bw*bz*Kvalid ; NHWC store + atomic stats
    float aw = pw[1], bw = pw[0] + 128.f * pw[1];
    float az, bz;
    if (MODE == 1) { az = zsc; bz = zmn + 128.f * zsc; }
    else           { az = pz[1]; bz = pz[0] + 128.f * pz[1]; }
    float caa = aw * az, cR = aw * bz, cC = bw * az, cK = bw * bz;
    int cco[2]; float rr0[2]; float t8v[2][8];
#pragma unroll
    for (int ni = 0; ni < 2; ni++) {
        cco[ni] = cob + wn * 32 + ni * 16 + l15;
        rr0[ni] = R[cco[ni]];
        if (MODE == 1) {
#pragma unroll
            for (int p = 0; p < 8; p++) t8v[ni][p] = T8[cco[ni] * 8 + p];
        }
    }
    float ssm[2] = {0.f, 0.f}, smnv[2] = {INFINITY, INFINITY}, smxv[2] = {-INFINITY, -INFINITY};
#pragma unroll
    for (int mi = 0; mi < 4; mi++)
#pragma unroll
        for (int reg = 0; reg < 4; reg++) {
            int j = jb + wm * 64 + mi * 16 + kq * 4 + reg;
            int n = j / 196, hw = j - n * 196;
            float constterm, cjv;
            float pt = 0.f, pb = 0.f, pl = 0.f, pr = 0.f, ctl = 0.f, ctr = 0.f, cbl = 0.f, cbr = 0.f;
            if (MODE == 1) {
                int h = hw / 14, w = hw - (hw / 14) * 14;
                pt = (h == 0) ? 1.f : 0.f;  pb = (h == 13) ? 1.f : 0.f;
                pl = (w == 0) ? 1.f : 0.f;  pr = (w == 13) ? 1.f : 0.f;
                ctl = pt * pl; ctr = pt * pr; cbl = pb * pl; cbr = pb * pr;
                float miss = 3.f * (pt + pb + pl + pr) - (ctl + ctr + cbl + cbr);
                constterm = cK * (256.f * (9.f - miss));
                cjv = Vl[j - jb];
            } else {
                constterm = cK * (float)K;
                cjv = Cj[j];
            }
#pragma unroll
            for (int ni = 0; ni < 2; ni++) {
                float rsum = rr0[ni];
                if (MODE == 1)
                    rsum -= pt * t8v[ni][0] + pb * t8v[ni][1] + pl * t8v[ni][2] + pr * t8v[ni][3]
                          - ctl * t8v[ni][4] - ctr * t8v[ni][5] - cbl * t8v[ni][6] - cbr * t8v[ni][7];
                float v = caa * (float)acc[mi][ni][reg] + cR * rsum + cC * cjv + constterm;
                outNHWC[(size_t)j * 256 + cco[ni]] = v;
                ssm[ni] += v;
                smnv[ni] = fminf(smnv[ni], v);
                smxv[ni] = fmaxf(smxv[ni], v);
            }
        }
#pragma unroll
    for (int ni = 0; ni < 2; ni++) {
        float s = ssm[ni], mn = smnv[ni], mx = smxv[ni];
        s += __shfl_xor(s, 16, 64); s += __shfl_xor(s, 32, 64);
        mn = fminf(mn, __shfl_xor(mn, 16, 64)); mn = fminf(mn, __shfl_xor(mn, 32, 64));
        mx = fmaxf(mx, __shfl_xor(mx, 16, 64)); mx = fmaxf(mx, __shfl_xor(mx, 32, 64));
        if (kq == 0) {
            int cl = wn * 32 + ni * 16 + l15;
            Lst[wm][cl][0] = s; Lst[wm][cl][1] = mn; Lst[wm][cl][2] = mx;
        }
    }
    __syncthreads();
    if (tid < 64) {
        float s  = Lst[0][tid][0] + Lst[1][tid][0];
        float mn = fminf(Lst[0][tid][1], Lst[1][tid][1]);
        float mx = fmaxf(Lst[0][tid][2], Lst[1][tid][2]);
        int co = cob + tid;
        atomicAdd(&Sumd[co], (double)s);
        atomicMin(&Mnk[co], fkey(mn));
        atomicMax(&Mxk[co], fkey(mx));
    }
}

// ---------------- conv3: i8 MFMA, M=128 j, N=128 co, K=256, INLINE stage-2 quant ----------------
// Replaces k_codeE<0> + z2c/CZ round-trip: each block reads OUT fp32 rows
// [jb..jb+128) x 256 ch (full K -> complete rows), quantizes BIT-IDENTICALLY to
// the deleted kernel (same stage_params math, same codef, same shfl_down rowsum
// order), ds_writes codes into the exact swizzled LDS image glds16 produced
// (write-side XOR g^(r&7); 64 distinct words/row -> conflict-free), and keeps
// per-row code-sums in CjL. OUT is L3-resident (conv2 just wrote it); the x8
// cob redundancy stays on one XCD's L2 (XCD-grouped grid).
__global__ __launch_bounds__(256, 2) void k_conv3(const signed char* __restrict__ Wts,
                                                  const float* __restrict__ Osrc,
                                                  const float* __restrict__ R,
                                                  const float* __restrict__ pw,
                                                  const float* __restrict__ pzg, const float* __restrict__ pzb,
                                                  const double* __restrict__ pzsum,
                                                  const unsigned* __restrict__ pzmn,
                                                  const unsigned* __restrict__ pzmx, float scale_fix,
                                                  float* __restrict__ out,
                                                  double* __restrict__ Sumd, unsigned* __restrict__ Mnk,
                                                  unsigned* __restrict__ Mxk) {
    __shared__ __align__(16) signed char As[32768];   // acts codes: 128 j x 256B (ds_write)
    __shared__ __align__(16) signed char Bs[32768];   // wts : 128 co x 256B (glds16)
    __shared__ float Lst[2][128][3];
    __shared__ float pscr[8];
    __shared__ __align__(16) float lmean[256];
    __shared__ __align__(16) float lsg[256];
    __shared__ __align__(16) float lbeta[256];
    __shared__ __align__(16) float CjL[128];
    int tid = threadIdx.x, lane = tid & 63, wave = tid >> 6;
    int wm = wave >> 1, wn = wave & 1;
    int bid = blockIdx.x;
    int xcd = bid & 7, slot = bid >> 3;
    int tile = xcd * 98 + slot;
    int jb = (tile >> 3) * 128, cob = (tile & 7) * 128;
    int sr = tid >> 4, spos = tid & 15;

    // B staging first: latency hides under stage_params + quant loop
#pragma unroll
    for (int p = 0; p < 8; p++) {
        int row = p * 16 + sr;
        int cg = spos ^ (row & 7);
        glds16(Wts + (size_t)(cob + row) * 256 + cg * 16, &Bs[p * 4096 + tid * 16]);
    }
    lbeta[tid] = pzb[tid];

    float zmn, zsc;
    stage_params<256>(pzg, pzb, pzsum, pzmn, pzmx, scale_fix, lmean, lsg, pscr, zmn, zsc);
    // lmean/lsg/lbeta visible: stage_params ends with blk_minmax (__syncthreads)

    // A: per iter k, wave w quantizes row r = 4k+w (wave-coalesced 1 KB row read)
    {
        int g = lane >> 2;             // 16B group within row
        int sub = (lane & 3) << 2;     // byte offset within group
        for (int k = 0; k < 32; k++) {
            int r = k * 4 + wave;
            const float* orow = Osrc + (size_t)(jb + r) * 256 + lane * 4;
            float4 v = *(const float4*)orow;
            int c0 = lane * 4;
            float q0 = codef((v.x - lmean[c0])     * lsg[c0]     + lbeta[c0],     zmn, zsc);
            float q1 = codef((v.y - lmean[c0 + 1]) * lsg[c0 + 1] + lbeta[c0 + 1], zmn, zsc);
            float q2 = codef((v.z - lmean[c0 + 2]) * lsg[c0 + 2] + lbeta[c0 + 2], zmn, zsc);
            float q3 = codef((v.w - lmean[c0 + 3]) * lsg[c0 + 3] + lbeta[c0 + 3], zmn, zsc);
            *(int*)&As[r * 256 + ((g ^ (r & 7)) << 4) + sub] = pack4(q0, q1, q2, q3);
            float s = q0 + q1 + q2 + q3;
            for (int o = 32; o; o >>= 1) s += __shfl_down(s, o, 64);
            if (lane == 0) CjL[r] = s;
        }
    }
    __syncthreads();   // drains Bs glds16 (vmcnt) + As/CjL ds_writes

    int4v acc[4][4];
#pragma unroll
    for (int mi = 0; mi < 4; mi++)
#pragma unroll
        for (int ni = 0; ni < 4; ni++) acc[mi][ni] = (int4v)0;

    int l15 = lane & 15, kq = lane >> 4, sw = l15 & 7;
#pragma unroll
    for (int kc = 0; kc < 4; kc++) {
        int col = ((kc * 4 + kq) ^ sw) << 4;
        int4v a[4], bb[4];
#pragma unroll
        for (int mi = 0; mi < 4; mi++)
            a[mi] = *(const int4v*)&As[(wm * 64 + mi * 16 + l15) * 256 + col];
#pragma unroll
        for (int ni = 0; ni < 4; ni++)
            bb[ni] = *(const int4v*)&Bs[(wn * 64 + ni * 16 + l15) * 256 + col];
#pragma unroll
        for (int mi = 0; mi < 4; mi++)
#pragma unroll
            for (int ni = 0; ni < 4; ni++)
                acc[mi][ni] = __builtin_amdgcn_mfma_i32_16x16x64_i8(a[mi], bb[ni], acc[mi][ni], 0, 0, 0);
    }

    float aw = pw[1], bw = pw[0] + 128.f * pw[1];
    float az = zsc, bz = zmn + 128.f * zsc;
    float caa = aw * az, cR = aw * bz, cC = bw * az, cK = bw * bz;
    int coA[4]; float rA[4];
#pragma unroll
    for (int ni = 0; ni < 4; ni++) {
        coA[ni] = cob + wn * 64 + ni * 16 + l15;
        rA[ni] = R[coA[ni]];
    }
    float ps[4], pmn[4], pmx[4];
#pragma unroll
    for (int ni = 0; ni < 4; ni++) { ps[ni] = 0.f; pmn[ni] = INFINITY; pmx[ni] = -INFINITY; }
#pragma unroll
    for (int mi = 0; mi < 4; mi++) {
        int j0 = jb + wm * 64 + mi * 16 + kq * 4;
        int n = j0 / 196, hh = j0 - n * 196;
        float4 cj = *(const float4*)&CjL[wm * 64 + mi * 16 + kq * 4];
#pragma unroll
        for (int ni = 0; ni < 4; ni++) {
            float base = cR * rA[ni] + cK * 256.f;
            float4 v;
            v.x = caa * (float)acc[mi][ni][0] + base + cC * cj.x;
            v.y = caa * (float)acc[mi][ni][1] + base + cC * cj.y;
            v.z = caa * (float)acc[mi][ni][2] + base + cC * cj.z;
            v.w = caa * (float)acc[mi][ni][3] + base + cC * cj.w;
            *(float4*)&out[((size_t)n * 1024 + coA[ni]) * 196 + hh] = v;
            ps[ni] += v.x + v.y + v.z + v.w;
            pmn[ni] = fminf(pmn[ni], fminf(fminf(v.x, v.y), fminf(v.z, v.w)));
            pmx[ni] = fmaxf(pmx[ni], fmaxf(fmaxf(v.x, v.y), fmaxf(v.z, v.w)));
        }
    }
#pragma unroll
    for (int ni = 0; ni < 4; ni++) {
        float s = ps[ni], mn = pmn[ni], mx = pmx[ni];
        s += __shfl_xor(s, 16, 64); s += __shfl_xor(s, 32, 64);
        mn = fminf(mn, __shfl_xor(mn, 16, 64)); mn = fminf(mn, __shfl_xor(mn, 32, 64));
        mx = fmaxf(mx, __shfl_xor(mx, 16, 64)); mx = fmaxf(mx, __shfl_xor(mx, 32, 64));
        if (kq == 0) {
            int cl = wn * 64 + ni * 16 + l15;
            Lst[wm][cl][0] = s; Lst[wm][cl][1] = mn; Lst[wm][cl][2] = mx;
        }
    }
    __syncthreads();
    if (tid < 128) {
        float s  = Lst[0][tid][0] + Lst[1][tid][0];
        float mn = fminf(Lst[0][tid][1], Lst[1][tid][1]);
        float mx = fmaxf(Lst[0][tid][2], Lst[1][tid][2]);
        int co = cob + tid;
        atomicAdd(&Sumd[co], (double)s);
        atomicMin(&Mnk[co], fkey(mn));
        atomicMax(&Mxk[co], fkey(mx));
    }
}

// ---------------- final: out = fq(x) + fq(norm3(out3)) in place ----------------
// LDS-transposed xc (R7, verified): coalesced int stage reads, contiguous float4
// out read+write, LDS row stride 68 (odd multiple of 4 -> ~2-way banks, free).
__global__ __launch_bounds__(256) void k_final(const signed char* __restrict__ xc, float* __restrict__ out,
                                               const float* __restrict__ gamma, const float* __restrict__ beta,
                                               const double* __restrict__ sumd, const unsigned* __restrict__ mnk,
                                               const unsigned* __restrict__ mxk, float scale_fix,
                                               const float* __restrict__ sf) {
    __shared__ __align__(16) signed char lx[196 * 68 + 4];   // row stride 68 B
    __shared__ float lmean[1024];
    __shared__ float lsg[1024];
    __shared__ float scr[8];
    int t = threadIdx.x;
    int n = blockIdx.x >> 4, cg = blockIdx.x & 15;   // 64 n x 16 groups of 64 ch
    const signed char* xp = xc + (size_t)n * 200704 + cg * 64;
    // stage: 196 rows x 16 ints (64 B per hw row), coalesced
    for (int i = t; i < 3136; i += 256) {
        int row = i >> 4, col = i & 15;
        int v = *(const int*)(xp + (size_t)row * 1024 + col * 4);
        *(int*)&lx[row * 68 + col * 4] = v;
    }
    float qmn, qsc;
    stage_params<1024>(gamma, beta, sumd, mnk, mxk, scale_fix, lmean, lsg, scr, qmn, qsc);
    __syncthreads();
    float xmn = sf[8], xsc = sf[9];
    float xoff = xmn + 128.f * xsc;
    float4* op = (float4*)(out + ((size_t)n * 1024 + cg * 64) * 196);
    for (int idx = t; idx < 3136; idx += 256) {   // 64 ch x 49 float4, contiguous
        int c = idx / 49, f = idx - c * 49;
        int hw = f * 4;
        float4 ov = op[idx];
        int cc = cg * 64 + c;
        float m = lmean[cc], s = lsg[cc], b = beta[cc];
        const signed char* lr = &lx[hw * 68 + c];
        float4 r;
        r.x = (float)lr[0]   * xsc + xoff + fqv((ov.x - m) * s + b, qmn, qsc);
        r.y = (float)lr[68]  * xsc + xoff + fqv((ov.y - m) * s + b, qmn, qsc);
        r.z = (float)lr[136] * xsc + xoff + fqv((ov.z - m) * s + b, qmn, qsc);
        r.w = (float)lr[204] * xsc + xoff + fqv((ov.w - m) * s + b, qmn, qsc);
        op[idx] = r;
    }
}

extern "C" void kernel_launch(void* const* d_in, const int* in_sizes, int n_in,
                              void* d_out, int out_size, void* d_ws, size_t ws_size,
                              hipStream_t stream) {
    const float* x  = (const float*)d_in[0];
    const float* w1 = (const float*)d_in[1];
    const float* g1 = (const float*)d_in[2];
    const float* b1 = (const float*)d_in[3];
    const float* w2 = (const float*)d_in[4];
    const float* g2 = (const float*)d_in[5];
    const float* b2 = (const float*)d_in[6];
    const float* w3 = (const float*)d_in[7];
    const float* g3 = (const float*)d_in[8];
    const float* b3 = (const float*)d_in[9];
    float* out = (float*)d_out;

    float* W = (float*)d_ws;
    float* OUT = W + OF_OUT;
    signed char* xc  = (signed char*)(W + OF_XC);
    signed char* z1p = (signed char*)(W + OF_Z1P);
    signed char* wq1 = (signed char*)(W + OF_WQ1);
    signed char* wq2 = (signed char*)(W + OF_WQ2);
    signed char* wq3 = (signed char*)(W + OF_WQ3);
    float* R1 = W + OF_R1; float* R2 = W + OF_R2; float* R3 = W + OF_R3;
    float* T2 = W + OF_T2;
    float* CX = W + OF_CX; float* U2 = W + OF_U2;
    double* SD1 = (double*)(W + OF_SD1);
    double* SD2 = (double*)(W + OF_SD2);
    double* SD3 = (double*)(W + OF_SD3);
    unsigned* MN1 = (unsigned*)(W + OF_MN1); unsigned* MX1 = (unsigned*)(W + OF_MX1);
    unsigned* MN2 = (unsigned*)(W + OF_MN2); unsigned* MX2 = (unsigned*)(W + OF_MX2);
    unsigned* MN3 = (unsigned*)(W + OF_MN3); unsigned* MX3 = (unsigned*)(W + OF_MX3);
    float* Pmm = W + OF_PMM;
    float* S = W + OF_ST;

    const float scale_fix =
        (float)((0.5 * 0.35) * (1.0 + sqrt(M_PI * log(4.0))) / sqrt(2.0 * log(12544.0)));

    // fq minmax partials for x, w1, w2, w3 + all workspace init (no memsets)
    k_minmax_all<<<1280, 256, 0, stream>>>((const float4*)x, (const float4*)w1,
                                           (const float4*)w2, (const float4*)w3, Pmm, W);

    // x -> NHWC i8 codes + CX | weight codes + reductions | sf persist (one launch;
    // blocks derive fq params from Pmm in-block -> k_fqparams2 dispatch deleted)
    k_prep<<<3329, 256, 0, stream>>>(x, xc, Pmm, S, CX, w1, w2, w3, wq1, wq2, wq3, R1, R2, R3, T2);

    // conv1 -> OUT NHWC + atomic stage-1 stats (1D grid, XCD-grouped)
    k_conv12<0><<<392, 256, 0, stream>>>(xc, wq1, R1, nullptr, CX, S + 11, S + 8,
                                         nullptr, nullptr, nullptr, nullptr, nullptr, 0.f,
                                         OUT, 1024, SD1, MN1, MX1);
    // norm1 params recomputed in-block; codes + padded rowsums U2
    k_codeE<1><<<784, 256, 0, stream>>>(OUT, z1p, g1, b1, SD1, MN1, MX1, scale_fix, U2);

    // conv2 (pz recomputed from stage-1 stats; 9-tap via Vl LDS) -> OUT NHWC + stage-2 stats
    k_conv12<1><<<392, 256, 0, stream>>>(z1p, wq2, R2, T2, U2, S + 14, nullptr,
                                         g1, b1, SD1, MN1, MX1, scale_fix,
                                         OUT, 2304, SD2, MN2, MX2);

    // conv3 with INLINE stage-2 quantization (k_codeE<0> + z2c/CZ deleted)
    // -> d_out NCHW + stage-3 stats
    k_conv3<<<784, 256, 0, stream>>>(wq3, OUT, R3, S + 17,
                                     g2, b2, SD2, MN2, MX2, scale_fix,
                                     out, SD3, MN3, MX3);

    // final: stage-3 params in-block; out = fq(x from codes via LDS transpose) + fq(norm3(out))
    k_final<<<1024, 256, 0, stream>>>(xc, out, g3, b3, SD3, MN3, MX3, scale_fix, S);
}

// Round 10
// 235.179 us; speedup vs baseline: 1.1187x; 1.1187x over previous
//
#include <hip/hip_runtime.h>
#include <math.h>

#ifndef M_PI
#define M_PI 3.14159265358979323846
#endif

// Shapes: x [64,1024,14,14]; w1 [256,1024]; w2 [256,256,3,3]; w3 [1024,256]
#define NB   64
#define NCOL 12544

typedef __attribute__((ext_vector_type(4))) int int4v;

// ---------------- workspace layout (float offsets) ----------------
static const size_t OF_OUT = 0;            // conv1/conv2 fp32 NHWC out [12544][256]
static const size_t OF_XC  = 3211264;      // x codes i8 NHWC [64][196][1024]
static const size_t OF_Z1P = 6422528;      // z1 codes i8 padded [64][16][16][256]
static const size_t OF_Z2C = 7471104;      // z2 codes i8 [12544][256]
static const size_t OF_WQ1 = 8273920;      // w1 codes i8 [256][1024]
static const size_t OF_WQ2 = 8339456;      // w2 codes i8 [256][9*256]
static const size_t OF_WQ3 = 8486912;      // w3 codes i8 [1024][256]
static const size_t OF_R1  = 8552448;
static const size_t OF_R2  = 8552704;
static const size_t OF_R3  = 8552960;
static const size_t OF_T2  = 8553984;      // 256*8 tap aggregates
static const size_t OF_CX  = 8556032;      // 12544
static const size_t OF_U2  = 8568576;      // 16384 (padded rowsums [64][16][16])
static const size_t OF_CZ  = 8597504;      // 12544
// stage stats (compact):
static const size_t OF_SD1 = 8610048;      // double[256]  (512 floats)
static const size_t OF_SD2 = 8610560;      // double[256]
static const size_t OF_SD3 = 8611072;      // double[1024] (2048 floats)
static const size_t OF_MN1 = 8613120;      // uint[256] min keys
static const size_t OF_MX1 = 8613376;      // uint[256] max keys
static const size_t OF_MN2 = 8613632;
static const size_t OF_MX2 = 8613888;
static const size_t OF_MN3 = 8614144;      // uint[1024]
static const size_t OF_MX3 = 8615168;      // uint[1024]
static const size_t OF_PMM = 9061632;      // minmax partials
static const size_t OF_ST  = 9068800;      // 64 misc floats (fq params)

__device__ __forceinline__ float fqv(float v, float mn, float sc) {
    float t = (v - mn) / sc;
    t = fminf(fmaxf(t, 0.0f), 255.0f);
    return rintf(t) * sc + mn;
}
// centered code (integer-valued in [-128,127])
__device__ __forceinline__ float codef(float v, float mn, float sc) {
    float t = (v - mn) / sc;
    t = fminf(fmaxf(t, 0.0f), 255.0f);
    return rintf(t) - 128.0f;
}
__device__ __forceinline__ unsigned short f2bf(float f) { return (unsigned short)(__float_as_uint(f) >> 16); }
__device__ __forceinline__ float bf2f(unsigned short u) { return __uint_as_float(((unsigned)u) << 16); }
__device__ __forceinline__ int pack4(float a, float b, float c, float d) {
    return (int)(unsigned char)(signed char)(int)a | ((int)(unsigned char)(signed char)(int)b << 8) |
           ((int)(unsigned char)(signed char)(int)c << 16) | ((int)(unsigned char)(signed char)(int)d << 24);
}
__device__ __forceinline__ void glds16(const void* g, void* l) {
    __builtin_amdgcn_global_load_lds((const __attribute__((address_space(1))) unsigned int*)g,
                                     (__attribute__((address_space(3))) unsigned int*)l, 16, 0, 0);
}
// monotone float<->uint key map (for atomicMin/Max on floats)
__device__ __forceinline__ unsigned fkey(float f) {
    unsigned u = __float_as_uint(f);
    return (u & 0x80000000u) ? ~u : (u | 0x80000000u);
}
__device__ __forceinline__ float unfkey(unsigned k) {
    unsigned u = (k & 0x80000000u) ? (k & 0x7FFFFFFFu) : ~k;
    return __uint_as_float(u);
}

// cooperative (256-thread) block min/max reduce; returns uniform values
__device__ __forceinline__ void blk_minmax(float& mn, float& mx, volatile float* scr) {
    for (int o = 32; o; o >>= 1) {
        mn = fminf(mn, __shfl_down(mn, o, 64));
        mx = fmaxf(mx, __shfl_down(mx, o, 64));
    }
    int lane = threadIdx.x & 63, wv = threadIdx.x >> 6;
    __syncthreads();
    if (lane == 0) { scr[wv] = mn; scr[4 + wv] = mx; }
    __syncthreads();
    mn = fminf(fminf(scr[0], scr[1]), fminf(scr[2], scr[3]));
    mx = fmaxf(fmaxf(scr[4], scr[5]), fmaxf(scr[6], scr[7]));
}

// derive (mn, scale) of one tensor from its minmax partials (exact: fmin/fmax
// reductions are order-independent -> bit-identical to the old k_fqparams2).
__device__ __forceinline__ void derive_fq(const float* __restrict__ Pmm, int base, int nb,
                                          volatile float* scr, float& mn_o, float& sc_o) {
    float mn = INFINITY, mx = -INFINITY;
    for (int i = threadIdx.x; i < nb; i += 256) {
        mn = fminf(mn, Pmm[base + 2 * i]);
        mx = fmaxf(mx, Pmm[base + 2 * i + 1]);
    }
    blk_minmax(mn, mx, scr);
    mn_o = mn;
    sc_o = fmaxf((mx - mn) / 255.0f, 1e-8f);
}

// recompute range_norm params of a finished stage from compact stats.
template <int C>
__device__ void stage_params(const float* __restrict__ gamma, const float* __restrict__ beta,
                             const double* __restrict__ sumd, const unsigned* __restrict__ mnk,
                             const unsigned* __restrict__ mxk, float scale_fix,
                             float* lmean, float* lsg, volatile float* scr,
                             float& zmn, float& zsc) {
    int t = threadIdx.x;
    float gmn = INFINITY, gmx = -INFINITY;
    for (int c = t; c < C; c += 256) {
        float g = gamma[c];
        gmn = fminf(gmn, g); gmx = fmaxf(gmx, g);
    }
    blk_minmax(gmn, gmx, scr);
    float gsc = fmaxf((gmx - gmn) / 255.0f, 1e-8f);
    float qmn = INFINITY, qmx = -INFINITY;
    for (int c = t; c < C; c += 256) {
        float mean = (float)sumd[c] / 12544.0f;
        float cmn = unfkey(mnk[c]), cmx = unfkey(mxk[c]);
        float rng = cmx - cmn;
        float qg = fqv(gamma[c], gmn, gsc);
        float s = qg / (rng * scale_fix + 1e-5f);
        if (lmean) { lmean[c] = mean; lsg[c] = s; }
        float b = beta[c];
        float lo = (cmn - mean) * s + b;
        float hi = (cmx - mean) * s + b;
        qmn = fminf(qmn, fminf(lo, hi));
        qmx = fmaxf(qmx, fmaxf(lo, hi));
    }
    blk_minmax(qmn, qmx, scr);
    zmn = qmn;
    zsc = fmaxf((qmx - qmn) / 255.0f, 1e-8f);
}

// ---------------- fused min/max over 4 tensors -> per-block partials + workspace init ----------------
__global__ __launch_bounds__(256) void k_minmax_all(const float4* __restrict__ x, const float4* __restrict__ w1,
                                                    const float4* __restrict__ w2, const float4* __restrict__ w3,
                                                    float* __restrict__ Pmm, float* __restrict__ Wf) {
    // --- init section: zero z1p/CX/U2 + stage stats, seed min/max keys ---
    {
        unsigned g = blockIdx.x * 256 + threadIdx.x;   // 0..327679
        int* zp = (int*)(Wf + OF_Z1P);
        for (unsigned i = g; i < 1048576u; i += 327680u) zp[i] = 0;
        if (g < 12544u) Wf[OF_CX + g] = 0.0f;
        if (g < 16384u) Wf[OF_U2 + g] = 0.0f;
        if (g < 3072u)  ((int*)(Wf + OF_SD1))[g] = 0;
        if (g < 256u) {
            ((unsigned*)(Wf + OF_MN1))[g] = 0xFF800000u;
            ((unsigned*)(Wf + OF_MX1))[g] = 0x007FFFFFu;
            ((unsigned*)(Wf + OF_MN2))[g] = 0xFF800000u;
            ((unsigned*)(Wf + OF_MX2))[g] = 0x007FFFFFu;
        }
        if (g < 1024u) {
            ((unsigned*)(Wf + OF_MN3))[g] = 0xFF800000u;
            ((unsigned*)(Wf + OF_MX3))[g] = 0x007FFFFFu;
        }
    }
    int b = blockIdx.x;
    const float4* p; int lb, nb, n4, base;
    if (b < 1024)      { p = x;  lb = b;        nb = 1024; n4 = 3211264; base = 0; }
    else if (b < 1088) { p = w1; lb = b - 1024; nb = 64;   n4 = 65536;   base = 2048; }
    else if (b < 1216) { p = w2; lb = b - 1088; nb = 128;  n4 = 147456;  base = 2176; }
    else               { p = w3; lb = b - 1216; nb = 64;   n4 = 65536;   base = 2432; }
    float mn = INFINITY, mx = -INFINITY;
    for (int i = lb * 256 + threadIdx.x; i < n4; i += nb * 256) {
        float4 v = p[i];
        mn = fminf(mn, fminf(fminf(v.x, v.y), fminf(v.z, v.w)));
        mx = fmaxf(mx, fmaxf(fmaxf(v.x, v.y), fmaxf(v.z, v.w)));
    }
    for (int o = 32; o; o >>= 1) {
        mn = fminf(mn, __shfl_down(mn, o, 64));
        mx = fmaxf(mx, __shfl_down(mx, o, 64));
    }
    __shared__ float smn[4], smx[4];
    int lane = threadIdx.x & 63, w = threadIdx.x >> 6;
    if (lane == 0) { smn[w] = mn; smx[w] = mx; }
    __syncthreads();
    if (threadIdx.x == 0) {
        for (int i = 1; i < 4; i++) { mn = fminf(mn, smn[i]); mx = fmaxf(mx, smx[i]); }
        Pmm[base + lb * 2]     = mn;
        Pmm[base + lb * 2 + 1] = mx;
    }
}

// ---------------- k_prep: x->NHWC i8 codes + CX | weight coding | sf persist ----------------
// Merged k_code0 (0..1791) + k_wcode_all (1792..3071 1x1, 3072..3327 3x3) +
// k_fqparams2 (block 3328 persists sf for downstream kernels). All blocks derive
// their own fq params from Pmm in-block (fmin/fmax reduce: bit-exact).
__global__ __launch_bounds__(256) void k_prep(const float* __restrict__ x, signed char* __restrict__ xdst,
                                              const float* __restrict__ Pmm, float* __restrict__ sf,
                                              float* __restrict__ CX,
                                              const float* __restrict__ w1, const float* __restrict__ w2,
                                              const float* __restrict__ w3,
                                              signed char* __restrict__ wq1, signed char* __restrict__ wq2,
                                              signed char* __restrict__ wq3,
                                              float* __restrict__ R1, float* __restrict__ R2,
                                              float* __restrict__ R3, float* __restrict__ T8) {
    __shared__ float scr8[8];
    int t = threadIdx.x;
    int lane = t & 63, wv = t >> 6;
    if (blockIdx.x == 3328) {
        // persist fq params (old k_fqparams2 body) for conv1/conv3/final
        __shared__ float sa[4], sb[4];
        const int nbs[4]   = {1024, 64, 128, 64};
        const int bases[4] = {0, 2048, 2176, 2432};
        for (int ten = 0; ten < 4; ten++) {
            float mn = INFINITY, mx = -INFINITY;
            for (int i = t; i < nbs[ten]; i += 256) {
                mn = fminf(mn, Pmm[bases[ten] + 2 * i]);
                mx = fmaxf(mx, Pmm[bases[ten] + 2 * i + 1]);
            }
            for (int o = 32; o; o >>= 1) {
                mn = fminf(mn, __shfl_down(mn, o, 64));
                mx = fmaxf(mx, __shfl_down(mx, o, 64));
            }
            if (lane == 0) { sa[wv] = mn; sb[wv] = mx; }
            __syncthreads();
            if (t == 0) {
                mn = fminf(fminf(sa[0], sa[1]), fminf(sa[2], sa[3]));
                mx = fmaxf(fmaxf(sb[0], sb[1]), fmaxf(sb[2], sb[3]));
                sf[8 + 3 * ten] = mn;
                sf[9 + 3 * ten] = fmaxf((mx - mn) / 255.0f, 1e-8f);
            }
            __syncthreads();
        }
        return;
    }
    if (blockIdx.x < 1792) {
        // ---- code0 unit ----
        float qmn, qsc;
        derive_fq(Pmm, 0, 1024, scr8, qmn, qsc);
        __shared__ unsigned short lt[28][264];
        int u = blockIdx.x;
        int n = u / 28, r = u - n * 28;
        int hw0 = (r % 7) * 28, cq = (r / 7) * 256;
        const float* sp = x + ((size_t)n * 1024 + cq) * 196 + hw0;
        for (int i = t; i < 7168; i += 256) {
            int c = i / 28, hw = i - c * 28;
            lt[hw][c] = f2bf(codef(sp[(size_t)c * 196 + hw], qmn, qsc));
        }
        __syncthreads();
        int c0 = lane * 4;
#pragma unroll
        for (int s = 0; s < 7; s++) {
            int i = s * 4 + wv;
            int pk = pack4(bf2f(lt[i][c0]), bf2f(lt[i][c0 + 1]), bf2f(lt[i][c0 + 2]), bf2f(lt[i][c0 + 3]));
            *(int*)&xdst[((size_t)n * 196 + hw0 + i) * 1024 + cq + c0] = pk;
        }
        for (int i = wv; i < 28; i += 4) {
            float s = bf2f(lt[i][lane]) + bf2f(lt[i][lane + 64]) +
                      bf2f(lt[i][lane + 128]) + bf2f(lt[i][lane + 192]);
            for (int o = 32; o; o >>= 1) s += __shfl_down(s, o, 64);
            if (lane == 0) atomicAdd(&CX[n * 196 + hw0 + i], s);
        }
        return;
    }
    // ---- wcode unit ----
    __shared__ float sh[64];
    int b = blockIdx.x - 1792;
    if (b < 1280) {
        const float* w; signed char* wc; float* R; int K, co;
        float mn, s;
        if (b < 256) { w = w1; wc = wq1; R = R1; K = 1024; co = b;       derive_fq(Pmm, 2048, 64, scr8, mn, s); }
        else         { w = w3; wc = wq3; R = R3; K = 256;  co = b - 256; derive_fq(Pmm, 2432, 64, scr8, mn, s); }
        float sum = 0.f;
        for (int k0 = t * 4; k0 < K; k0 += 1024) {
            float4 v = *(const float4*)&w[(size_t)co * K + k0];
            float c0 = codef(v.x, mn, s), c1 = codef(v.y, mn, s), c2 = codef(v.z, mn, s), c3 = codef(v.w, mn, s);
            *(int*)&wc[(size_t)co * K + k0] = pack4(c0, c1, c2, c3);
            sum += c0 + c1 + c2 + c3;
        }
        for (int o = 32; o; o >>= 1) sum += __shfl_down(sum, o, 64);
        if (lane == 0) sh[wv] = sum;
        __syncthreads();
        if (t == 0) R[co] = sh[0] + sh[1] + sh[2] + sh[3];
    } else {
        float mn, s;
        derive_fq(Pmm, 2176, 128, scr8, mn, s);
        int co = b - 1280, ci = t;
        float tp[9];
#pragma unroll
        for (int p = 0; p < 9; p++) {
            float c = codef(w2[((size_t)co * 256 + ci) * 9 + p], mn, s);
            wq2[(size_t)co * 2304 + p * 256 + ci] = (signed char)(int)c;
            tp[p] = c;
        }
        float* red = sh;      // [4][9]
        float* sT = sh + 40;  // [9]
#pragma unroll
        for (int p = 0; p < 9; p++) {
            float v = tp[p];
            for (int o = 32; o; o >>= 1) v += __shfl_down(v, o, 64);
            if (lane == 0) red[wv * 9 + p] = v;
        }
        __syncthreads();
        if (ci < 9) sT[ci] = red[ci] + red[9 + ci] + red[18 + ci] + red[27 + ci];
        __syncthreads();
        if (ci == 0) {
            float T0 = sT[0], T1 = sT[1], T2 = sT[2], T3 = sT[3],
                  T5 = sT[5], T6 = sT[6], T7 = sT[7], T8v = sT[8];
            R2[co] = T0 + T1 + T2 + T3 + sT[4] + T5 + T6 + T7 + T8v;
            float* o = &T8[co * 8];
            o[0] = T0 + T1 + T2;   // top
            o[1] = T6 + T7 + T8v;  // bot
            o[2] = T0 + T3 + T6;   // left
            o[3] = T2 + T5 + T8v;  // right
            o[4] = T0; o[5] = T2; o[6] = T6; o[7] = T8v;
        }
    }
}

// ---------------- NHWC elementwise norm+quant -> i8 codes + rowsum ----------------
template <int PAD>
__global__ __launch_bounds__(256) void k_codeE(const float* __restrict__ src, signed char* __restrict__ dst,
                                               const float* __restrict__ gamma, const float* __restrict__ beta_g,
                                               const double* __restrict__ sumd, const unsigned* __restrict__ mnk,
                                               const unsigned* __restrict__ mxk, float scale_fix,
                                               float* __restrict__ rowsum) {
    __shared__ __align__(16) float lmean[256];
    __shared__ __align__(16) float lsg[256];
    __shared__ float scr[8];
    float qmn, qsc;
    stage_params<256>(gamma, beta_g, sumd, mnk, mxk, scale_fix, lmean, lsg, scr, qmn, qsc);
    __syncthreads();
    int t = threadIdx.x, lane = t & 63, wv = t >> 6;
    int c4 = lane * 4;
    float4 m4 = *(const float4*)&lmean[c4];
    float4 s4 = *(const float4*)&lsg[c4];
    float4 b4 = *(const float4*)&beta_g[c4];
#pragma unroll
    for (int r = 0; r < 4; r++) {
        int j = blockIdx.x * 16 + wv * 4 + r;
        float4 v = *(const float4*)&src[(size_t)j * 256 + c4];
        float c0 = codef((v.x - m4.x) * s4.x + b4.x, qmn, qsc);
        float c1 = codef((v.y - m4.y) * s4.y + b4.y, qmn, qsc);
        float c2 = codef((v.z - m4.z) * s4.z + b4.z, qmn, qsc);
        float c3 = codef((v.w - m4.w) * s4.w + b4.w, qmn, qsc);
        int n = j / 196, hw = j - n * 196, h = hw / 14, w = hw - (hw / 14) * 14;
        size_t di;
        if (PAD) di = (((size_t)n * 16 + h + 1) * 16 + (w + 1)) * 256 + c4;
        else     di = (size_t)j * 256 + c4;
        *(int*)&dst[di] = pack4(c0, c1, c2, c3);
        float s = c0 + c1 + c2 + c3;
        for (int o = 32; o; o >>= 1) s += __shfl_down(s, o, 64);
        if (lane == 0) {
            if (PAD) rowsum[((size_t)n * 16 + h + 1) * 16 + (w + 1)] = s;
            else     rowsum[j] = s;
        }
    }
}

// ---------------- conv1/conv2: i8 MFMA, M=128 j, N=64 co, BK=128, dbuf ----------------
// 1D grid 392 with XCD-grouping swizzle (R4: same-A blocks on one XCD -> L2 reuse).
// MODE 1: 9-tap of U2 computed ONCE per block into Vl LDS.
template <int MODE>
__global__ __launch_bounds__(256, 2) void k_conv12(const signed char* __restrict__ Acts,
                                                   const signed char* __restrict__ Wts,
                                                   const float* __restrict__ R, const float* __restrict__ T8,
                                                   const float* __restrict__ Cj,
                                                   const float* __restrict__ pw, const float* __restrict__ pz,
                                                   const float* __restrict__ pzg, const float* __restrict__ pzb,
                                                   const double* __restrict__ pzsum,
                                                   const unsigned* __restrict__ pzmn,
                                                   const unsigned* __restrict__ pzmx, float scale_fix,
                                                   float* __restrict__ outNHWC, int K,
                                                   double* __restrict__ Sumd, unsigned* __restrict__ Mnk,
                                                   unsigned* __restrict__ Mxk) {
    __shared__ __align__(16) signed char As[2 * 16384];   // 2 x 128 rows x 128B
    __shared__ __align__(16) signed char Bs[2 * 8192];    // 2 x 64 rows x 128B
    __shared__ float Lst[2][64][3];
    __shared__ float pscr[8];
    __shared__ float Vl[128];
    int tid = threadIdx.x, lane = tid & 63, wave = tid >> 6;
    int wm = wave >> 1, wn = wave & 1;
    // XCD-grouping swizzle (392 = 49 tiles/XCD * 8 XCDs, bijective)
    int bid = blockIdx.x;
    int xcd = bid & 7, slot = bid >> 3;
    int tile = xcd * 49 + slot;
    int jb = (tile >> 2) * 128, cob = (tile & 3) * 64;
    int sr = tid >> 3, spos = tid & 7, sc = spos ^ (sr & 7);

    const signed char* aq[4];
#pragma unroll
    for (int q = 0; q < 4; q++) {
        int j = jb + q * 32 + sr;
        if (MODE == 0) aq[q] = Acts + (size_t)j * K + sc * 16;
        else {
            int n = j / 196, hw = j - n * 196, h = hw / 14, w = hw - (hw / 14) * 14;
            aq[q] = Acts + (((size_t)n * 16 + h) * 16 + w) * 256 + sc * 16;
        }
    }
    const signed char* bq[2];
#pragma unroll
    for (int q = 0; q < 2; q++) bq[q] = Wts + (size_t)(cob + q * 32 + sr) * K + sc * 16;

    int nk = K >> 7;
    auto stage = [&](int b, int ks) {
        size_t koA;
        if (MODE == 0) koA = (size_t)ks << 7;
        else {
            int k = ks << 7;
            int p = k >> 8, kin = k & 255;
            int rr = p / 3, ss = p - 3 * rr;
            koA = (size_t)(rr * 16 + ss) * 256 + kin;
        }
#pragma unroll
        for (int q = 0; q < 4; q++)
            glds16(aq[q] + koA, &As[b * 16384 + (q * 32 + sr) * 128 + spos * 16]);
#pragma unroll
        for (int q = 0; q < 2; q++)
            glds16(bq[q] + ((size_t)ks << 7), &Bs[b * 8192 + (q * 32 + sr) * 128 + spos * 16]);
    };

    // issue stage 0 first so its latency hides under the params/Vl work (MODE 1)
    stage(0, 0);
    float zmn = 0.f, zsc = 0.f;
    if (MODE == 1) {
        stage_params<256>(pzg, pzb, pzsum, pzmn, pzmx, scale_fix, nullptr, nullptr, pscr, zmn, zsc);
        if (tid < 128) {
            int j = jb + tid;
            int n_ = j / 196, hw_ = j - n_ * 196, h_ = hw_ / 14, w_ = hw_ - (hw_ / 14) * 14;
            const float* u = Cj + n_ * 256 + h_ * 16 + w_;
            Vl[tid] = u[0] + u[1] + u[2] + u[16] + u[17] + u[18] + u[32] + u[33] + u[34];
        }
    }

    int4v acc[4][2];
#pragma unroll
    for (int mi = 0; mi < 4; mi++)
#pragma unroll
        for (int ni = 0; ni < 2; ni++) acc[mi][ni] = (int4v)0;

    int l15 = lane & 15, kq = lane >> 4, sw = l15 & 7;
    for (int ks = 0; ks < nk; ks++) {
        __syncthreads();
        if (ks + 1 < nk) stage((ks + 1) & 1, ks + 1);
        int b = ks & 1;
#pragma unroll
        for (int kc = 0; kc < 2; kc++) {
            int col = ((kc * 4 + kq) ^ sw) << 4;
            int4v a[4], bb[2];
#pragma unroll
            for (int mi = 0; mi < 4; mi++)
                a[mi] = *(const int4v*)&As[b * 16384 + (wm * 64 + mi * 16 + l15) * 128 + col];
#pragma unroll
            for (int ni = 0; ni < 2; ni++)
                bb[ni] = *(const int4v*)&Bs[b * 8192 + (wn * 32 + ni * 16 + l15) * 128 + col];
#pragma unroll
            for (int mi = 0; mi < 4; mi++)
#pragma unroll
                for (int ni = 0; ni < 2; ni++)
                    acc[mi][ni] = __builtin_amdgcn_mfma_i32_16x16x64_i8(a[mi], bb[ni], acc[mi][ni], 0, 0, 0);
        }
    }

    // epilogue: value = aw*az*S + aw*bz*(R-PT) + bw*az*Cj + bw*bz*Kvalid ; NHWC store + atomic stats
    float aw = pw[1], bw = pw[0] + 128.f * pw[1];
    float az, bz;
    if (MODE == 1) { az = zsc; bz = zmn + 128.f * zsc; }
    else           { az = pz[1]; bz = pz[0] + 128.f * pz[1]; }
    float caa = aw * az, cR = aw * bz, cC = bw * az, cK = bw * bz;
    int cco[2]; float rr0[2]; float t8v[2][8];
#pragma unroll
    for (int ni = 0; ni < 2; ni++) {
        cco[ni] = cob + wn * 32 + ni * 16 + l15;
        rr0[ni] = R[cco[ni]];
        if (MODE == 1) {
#pragma unroll
            for (int p = 0; p < 8; p++) t8v[ni][p] = T8[cco[ni] * 8 + p];
        }
    }
    float ssm[2] = {0.f, 0.f}, smnv[2] = {INFINITY, INFINITY}, smxv[2] = {-INFINITY, -INFINITY};
#pragma unroll
    for (int mi = 0; mi < 4; mi++)
#pragma unroll
        for (int reg = 0; reg < 4; reg++) {
            int j = jb + wm * 64 + mi * 16 + kq * 4 + reg;
            int n = j / 196, hw = j - n * 196;
            float constterm, cjv;
            float pt = 0.f, pb = 0.f, pl = 0.f, pr = 0.f, ctl = 0.f, ctr = 0.f, cbl = 0.f, cbr = 0.f;
            if (MODE == 1) {
                int h = hw / 14, w = hw - (hw / 14) * 14;
                pt = (h == 0) ? 1.f : 0.f;  pb = (h == 13) ? 1.f : 0.f;
                pl = (w == 0) ? 1.f : 0.f;  pr = (w == 13) ? 1.f : 0.f;
                ctl = pt * pl; ctr = pt * pr; cbl = pb * pl; cbr = pb * pr;
                float miss = 3.f * (pt + pb + pl + pr) - (ctl + ctr + cbl + cbr);
                constterm = cK * (256.f * (9.f - miss));
                cjv = Vl[j - jb];
            } else {
                constterm = cK * (float)K;
                cjv = Cj[j];
            }
#pragma unroll
            for (int ni = 0; ni < 2; ni++) {
                float rsum = rr0[ni];
                if (MODE == 1)
                    rsum -= pt * t8v[ni][0] + pb * t8v[ni][1] + pl * t8v[ni][2] + pr * t8v[ni][3]
                          - ctl * t8v[ni][4] - ctr * t8v[ni][5] - cbl * t8v[ni][6] - cbr * t8v[ni][7];
                float v = caa * (float)acc[mi][ni][reg] + cR * rsum + cC * cjv + constterm;
                outNHWC[(size_t)j * 256 + cco[ni]] = v;
                ssm[ni] += v;
                smnv[ni] = fminf(smnv[ni], v);
                smxv[ni] = fmaxf(smxv[ni], v);
            }
        }
#pragma unroll
    for (int ni = 0; ni < 2; ni++) {
        float s = ssm[ni], mn = smnv[ni], mx = smxv[ni];
        s += __shfl_xor(s, 16, 64); s += __shfl_xor(s, 32, 64);
        mn = fminf(mn, __shfl_xor(mn, 16, 64)); mn = fminf(mn, __shfl_xor(mn, 32, 64));
        mx = fmaxf(mx, __shfl_xor(mx, 16, 64)); mx = fmaxf(mx, __shfl_xor(mx, 32, 64));
        if (kq == 0) {
            int cl = wn * 32 + ni * 16 + l15;
            Lst[wm][cl][0] = s; Lst[wm][cl][1] = mn; Lst[wm][cl][2] = mx;
        }
    }
    __syncthreads();
    if (tid < 64) {
        float s  = Lst[0][tid][0] + Lst[1][tid][0];
        float mn = fminf(Lst[0][tid][1], Lst[1][tid][1]);
        float mx = fmaxf(Lst[0][tid][2], Lst[1][tid][2]);
        int co = cob + tid;
        atomicAdd(&Sumd[co], (double)s);
        atomicMin(&Mnk[co], fkey(mn));
        atomicMax(&Mxk[co], fkey(mx));
    }
}

// ---------------- conv3: i8 MFMA, M=128 j, N=128 co, K=256 single stage (R7 form) ----------------
// 1D grid 784, XCD-grouping swizzle. Loads issued BEFORE stage_params.
// (R9's inline-quant variant REVERTED: x8 redundant quant + latency-serialized
// reduce + 401K LDS bank conflicts made conv3 61 us vs ~30. glds16 staging
// of precomputed z2c codes is the proven-fast path.)
__global__ __launch_bounds__(256, 2) void k_conv3(const signed char* __restrict__ Wts,
                                                  const signed char* __restrict__ Zc,
                                                  const float* __restrict__ R, const float* __restrict__ Cj,
                                                  const float* __restrict__ pw,
                                                  const float* __restrict__ pzg, const float* __restrict__ pzb,
                                                  const double* __restrict__ pzsum,
                                                  const unsigned* __restrict__ pzmn,
                                                  const unsigned* __restrict__ pzmx, float scale_fix,
                                                  float* __restrict__ out,
                                                  double* __restrict__ Sumd, unsigned* __restrict__ Mnk,
                                                  unsigned* __restrict__ Mxk) {
    __shared__ __align__(16) signed char As[32768];   // acts: 128 j x 256B
    __shared__ __align__(16) signed char Bs[32768];   // wts : 128 co x 256B
    __shared__ float Lst[2][128][3];
    __shared__ float pscr[8];
    int tid = threadIdx.x, lane = tid & 63, wave = tid >> 6;
    int wm = wave >> 1, wn = wave & 1;
    int bid = blockIdx.x;
    int xcd = bid & 7, slot = bid >> 3;
    int tile = xcd * 98 + slot;
    int jb = (tile >> 3) * 128, cob = (tile & 7) * 128;
    int sr = tid >> 4, spos = tid & 15;

#pragma unroll
    for (int p = 0; p < 8; p++) {
        int row = p * 16 + sr;
        int cg = spos ^ (row & 7);
        glds16(Zc + (size_t)(jb + row) * 256 + cg * 16, &As[p * 4096 + tid * 16]);
    }
#pragma unroll
    for (int p = 0; p < 8; p++) {
        int row = p * 16 + sr;
        int cg = spos ^ (row & 7);
        glds16(Wts + (size_t)(cob + row) * 256 + cg * 16, &Bs[p * 4096 + tid * 16]);
    }

    float zmn, zsc;
    stage_params<256>(pzg, pzb, pzsum, pzmn, pzmx, scale_fix, nullptr, nullptr, pscr, zmn, zsc);
    __syncthreads();

    int4v acc[4][4];
#pragma unroll
    for (int mi = 0; mi < 4; mi++)
#pragma unroll
        for (int ni = 0; ni < 4; ni++) acc[mi][ni] = (int4v)0;

    int l15 = lane & 15, kq = lane >> 4, sw = l15 & 7;
#pragma unroll
    for (int kc = 0; kc < 4; kc++) {
        int col = ((kc * 4 + kq) ^ sw) << 4;
        int4v a[4], bb[4];
#pragma unroll
        for (int mi = 0; mi < 4; mi++)
            a[mi] = *(const int4v*)&As[(wm * 64 + mi * 16 + l15) * 256 + col];
#pragma unroll
        for (int ni = 0; ni < 4; ni++)
            bb[ni] = *(const int4v*)&Bs[(wn * 64 + ni * 16 + l15) * 256 + col];
#pragma unroll
        for (int mi = 0; mi < 4; mi++)
#pragma unroll
            for (int ni = 0; ni < 4; ni++)
                acc[mi][ni] = __builtin_amdgcn_mfma_i32_16x16x64_i8(a[mi], bb[ni], acc[mi][ni], 0, 0, 0);
    }

    float aw = pw[1], bw = pw[0] + 128.f * pw[1];
    float az = zsc, bz = zmn + 128.f * zsc;
    float caa = aw * az, cR = aw * bz, cC = bw * az, cK = bw * bz;
    int coA[4]; float rA[4];
#pragma unroll
    for (int ni = 0; ni < 4; ni++) {
        coA[ni] = cob + wn * 64 + ni * 16 + l15;
        rA[ni] = R[coA[ni]];
    }
    float ps[4], pmn[4], pmx[4];
#pragma unroll
    for (int ni = 0; ni < 4; ni++) { ps[ni] = 0.f; pmn[ni] = INFINITY; pmx[ni] = -INFINITY; }
#pragma unroll
    for (int mi = 0; mi < 4; mi++) {
        int j0 = jb + wm * 64 + mi * 16 + kq * 4;
        int n = j0 / 196, hh = j0 - n * 196;
        float4 cj = *(const float4*)&Cj[j0];
#pragma unroll
        for (int ni = 0; ni < 4; ni++) {
            float base = cR * rA[ni] + cK * 256.f;
            float4 v;
            v.x = caa * (float)acc[mi][ni][0] + base + cC * cj.x;
            v.y = caa * (float)acc[mi][ni][1] + base + cC * cj.y;
            v.z = caa * (float)acc[mi][ni][2] + base + cC * cj.z;
            v.w = caa * (float)acc[mi][ni][3] + base + cC * cj.w;
            *(float4*)&out[((size_t)n * 1024 + coA[ni]) * 196 + hh] = v;
            ps[ni] += v.x + v.y + v.z + v.w;
            pmn[ni] = fminf(pmn[ni], fminf(fminf(v.x, v.y), fminf(v.z, v.w)));
            pmx[ni] = fmaxf(pmx[ni], fmaxf(fmaxf(v.x, v.y), fmaxf(v.z, v.w)));
        }
    }
#pragma unroll
    for (int ni = 0; ni < 4; ni++) {
        float s = ps[ni], mn = pmn[ni], mx = pmx[ni];
        s += __shfl_xor(s, 16, 64); s += __shfl_xor(s, 32, 64);
        mn = fminf(mn, __shfl_xor(mn, 16, 64)); mn = fminf(mn, __shfl_xor(mn, 32, 64));
        mx = fmaxf(mx, __shfl_xor(mx, 16, 64)); mx = fmaxf(mx, __shfl_xor(mx, 32, 64));
        if (kq == 0) {
            int cl = wn * 64 + ni * 16 + l15;
            Lst[wm][cl][0] = s; Lst[wm][cl][1] = mn; Lst[wm][cl][2] = mx;
        }
    }
    __syncthreads();
    if (tid < 128) {
        float s  = Lst[0][tid][0] + Lst[1][tid][0];
        float mn = fminf(Lst[0][tid][1], Lst[1][tid][1]);
        float mx = fmaxf(Lst[0][tid][2], Lst[1][tid][2]);
        int co = cob + tid;
        atomicAdd(&Sumd[co], (double)s);
        atomicMin(&Mnk[co], fkey(mn));
        atomicMax(&Mxk[co], fkey(mx));
    }
}

// ---------------- final: out = fq(x) + fq(norm3(out3)) in place ----------------
// LDS-transposed xc (R7, verified): coalesced int stage reads, contiguous float4
// out read+write, LDS row stride 68 (odd multiple of 4 -> ~2-way banks, free).
__global__ __launch_bounds__(256) void k_final(const signed char* __restrict__ xc, float* __restrict__ out,
                                               const float* __restrict__ gamma, const float* __restrict__ beta,
                                               const double* __restrict__ sumd, const unsigned* __restrict__ mnk,
                                               const unsigned* __restrict__ mxk, float scale_fix,
                                               const float* __restrict__ sf) {
    __shared__ __align__(16) signed char lx[196 * 68 + 4];   // row stride 68 B
    __shared__ float lmean[1024];
    __shared__ float lsg[1024];
    __shared__ float scr[8];
    int t = threadIdx.x;
    int n = blockIdx.x >> 4, cg = blockIdx.x & 15;   // 64 n x 16 groups of 64 ch
    const signed char* xp = xc + (size_t)n * 200704 + cg * 64;
    // stage: 196 rows x 16 ints (64 B per hw row), coalesced
    for (int i = t; i < 3136; i += 256) {
        int row = i >> 4, col = i & 15;
        int v = *(const int*)(xp + (size_t)row * 1024 + col * 4);
        *(int*)&lx[row * 68 + col * 4] = v;
    }
    float qmn, qsc;
    stage_params<1024>(gamma, beta, sumd, mnk, mxk, scale_fix, lmean, lsg, scr, qmn, qsc);
    __syncthreads();
    float xmn = sf[8], xsc = sf[9];
    float xoff = xmn + 128.f * xsc;
    float4* op = (float4*)(out + ((size_t)n * 1024 + cg * 64) * 196);
    for (int idx = t; idx < 3136; idx += 256) {   // 64 ch x 49 float4, contiguous
        int c = idx / 49, f = idx - c * 49;
        int hw = f * 4;
        float4 ov = op[idx];
        int cc = cg * 64 + c;
        float m = lmean[cc], s = lsg[cc], b = beta[cc];
        const signed char* lr = &lx[hw * 68 + c];
        float4 r;
        r.x = (float)lr[0]   * xsc + xoff + fqv((ov.x - m) * s + b, qmn, qsc);
        r.y = (float)lr[68]  * xsc + xoff + fqv((ov.y - m) * s + b, qmn, qsc);
        r.z = (float)lr[136] * xsc + xoff + fqv((ov.z - m) * s + b, qmn, qsc);
        r.w = (float)lr[204] * xsc + xoff + fqv((ov.w - m) * s + b, qmn, qsc);
        op[idx] = r;
    }
}

extern "C" void kernel_launch(void* const* d_in, const int* in_sizes, int n_in,
                              void* d_out, int out_size, void* d_ws, size_t ws_size,
                              hipStream_t stream) {
    const float* x  = (const float*)d_in[0];
    const float* w1 = (const float*)d_in[1];
    const float* g1 = (const float*)d_in[2];
    const float* b1 = (const float*)d_in[3];
    const float* w2 = (const float*)d_in[4];
    const float* g2 = (const float*)d_in[5];
    const float* b2 = (const float*)d_in[6];
    const float* w3 = (const float*)d_in[7];
    const float* g3 = (const float*)d_in[8];
    const float* b3 = (const float*)d_in[9];
    float* out = (float*)d_out;

    float* W = (float*)d_ws;
    float* OUT = W + OF_OUT;
    signed char* xc  = (signed char*)(W + OF_XC);
    signed char* z1p = (signed char*)(W + OF_Z1P);
    signed char* z2c = (signed char*)(W + OF_Z2C);
    signed char* wq1 = (signed char*)(W + OF_WQ1);
    signed char* wq2 = (signed char*)(W + OF_WQ2);
    signed char* wq3 = (signed char*)(W + OF_WQ3);
    float* R1 = W + OF_R1; float* R2 = W + OF_R2; float* R3 = W + OF_R3;
    float* T2 = W + OF_T2;
    float* CX = W + OF_CX; float* U2 = W + OF_U2; float* CZ = W + OF_CZ;
    double* SD1 = (double*)(W + OF_SD1);
    double* SD2 = (double*)(W + OF_SD2);
    double* SD3 = (double*)(W + OF_SD3);
    unsigned* MN1 = (unsigned*)(W + OF_MN1); unsigned* MX1 = (unsigned*)(W + OF_MX1);
    unsigned* MN2 = (unsigned*)(W + OF_MN2); unsigned* MX2 = (unsigned*)(W + OF_MX2);
    unsigned* MN3 = (unsigned*)(W + OF_MN3); unsigned* MX3 = (unsigned*)(W + OF_MX3);
    float* Pmm = W + OF_PMM;
    float* S = W + OF_ST;

    const float scale_fix =
        (float)((0.5 * 0.35) * (1.0 + sqrt(M_PI * log(4.0))) / sqrt(2.0 * log(12544.0)));

    // fq minmax partials for x, w1, w2, w3 + all workspace init (no memsets)
    k_minmax_all<<<1280, 256, 0, stream>>>((const float4*)x, (const float4*)w1,
                                           (const float4*)w2, (const float4*)w3, Pmm, W);

    // x -> NHWC i8 codes + CX | weight codes + reductions | sf persist (one launch;
    // blocks derive fq params from Pmm in-block -> k_fqparams2 dispatch deleted)
    k_prep<<<3329, 256, 0, stream>>>(x, xc, Pmm, S, CX, w1, w2, w3, wq1, wq2, wq3, R1, R2, R3, T2);

    // conv1 -> OUT NHWC + atomic stage-1 stats (1D grid, XCD-grouped)
    k_conv12<0><<<392, 256, 0, stream>>>(xc, wq1, R1, nullptr, CX, S + 11, S + 8,
                                         nullptr, nullptr, nullptr, nullptr, nullptr, 0.f,
                                         OUT, 1024, SD1, MN1, MX1);
    // norm1 params recomputed in-block; codes + padded rowsums U2
    k_codeE<1><<<784, 256, 0, stream>>>(OUT, z1p, g1, b1, SD1, MN1, MX1, scale_fix, U2);

    // conv2 (pz recomputed from stage-1 stats; 9-tap via Vl LDS) -> OUT NHWC + stage-2 stats
    k_conv12<1><<<392, 256, 0, stream>>>(z1p, wq2, R2, T2, U2, S + 14, nullptr,
                                         g1, b1, SD1, MN1, MX1, scale_fix,
                                         OUT, 2304, SD2, MN2, MX2);
    // stage-2 codes + rowsums (restored: the proven-fast path for conv3's A operand)
    k_codeE<0><<<784, 256, 0, stream>>>(OUT, z2c, g2, b2, SD2, MN2, MX2, scale_fix, CZ);

    // conv3 (R7 form: glds16-staged z2c) -> d_out NCHW + stage-3 stats
    k_conv3<<<784, 256, 0, stream>>>(wq3, z2c, R3, CZ, S + 17,
                                     g2, b2, SD2, MN2, MX2, scale_fix,
                                     out, SD3, MN3, MX3);

    // final: stage-3 params in-block; out = fq(x from codes via LDS transpose) + fq(norm3(out))
    k_final<<<1024, 256, 0, stream>>>(xc, out, g3, b3, SD3, MN3, MX3, scale_fix, S);
}